// Round 1
// baseline (167.790 us; speedup 1.0000x reference)
//
#include <hip/hip_runtime.h>
#include <stdint.h>
#include <stddef.h>

typedef _Float16 f16;
typedef _Float16 f16x8 __attribute__((ext_vector_type(8)));
typedef _Float16 f16x4 __attribute__((ext_vector_type(4)));
typedef float    f32x4 __attribute__((ext_vector_type(4)));

#define S_LEN 2048
#define DM    1024
#define NH    16
#define HD    64
#define NTOK  4096      // B*S
#define NQKV  3072      // 3*DM

// async global->LDS, 16B per lane. LDS dest is wave-uniform base + lane*16:
// passing &lds[tid*16] works (readfirstlane picks the wave base).
__device__ __forceinline__ void gl_lds16(const void* g, void* l) {
  __builtin_amdgcn_global_load_lds(
      (const __attribute__((address_space(1))) void*)g,
      (__attribute__((address_space(3))) void*)l, 16, 0, 0);
}

// ---------------- elementwise f32 -> f16 ----------------
__global__ __launch_bounds__(256) void cvt_f16_kernel(const float* __restrict__ in,
                                                      f16* __restrict__ out, int n) {
  int i = (blockIdx.x * 256 + threadIdx.x) * 8;
  if (i >= n) return;
  float4 a = *(const float4*)(in + i);
  float4 b = *(const float4*)(in + i + 4);
  f16x8 v = {(f16)a.x,(f16)a.y,(f16)a.z,(f16)a.w,(f16)b.x,(f16)b.y,(f16)b.z,(f16)b.w};
  *(f16x8*)(out + i) = v;
}

// ---------------- transpose+convert: in[R][C] f32 -> out[C][R] f16 ----------------
__global__ __launch_bounds__(256) void cvt_tr_kernel(const float* __restrict__ in,
                                                     f16* __restrict__ out, int R, int C) {
  __shared__ float t[32][33];
  int c0 = blockIdx.x * 32, r0 = blockIdx.y * 32;
  int tx = threadIdx.x, ty = threadIdx.y;
  #pragma unroll
  for (int i = 0; i < 4; ++i)
    t[ty + i*8][tx] = in[(size_t)(r0 + ty + i*8) * C + c0 + tx];
  __syncthreads();
  #pragma unroll
  for (int i = 0; i < 4; ++i)
    out[(size_t)(c0 + ty + i*8) * R + r0 + tx] = (f16)t[tx][ty + i*8];
}

// ---------------- 128x128x(BK=32) fp16 MFMA GEMM, A[M][1024] @ Bt[N][1024]^T ----------
// EPI 0: scatter epilogue -> q (pre-scaled 1/8), k as [bh][s][64], v transposed [bh][64][s]
// EPI 1: fp32 out + bias, row-major [M][1024]
template<int EPI>
__global__ __launch_bounds__(256) void gemm128_kernel(
    const f16* __restrict__ A, const f16* __restrict__ Bt,
    const float* __restrict__ bias,
    f16* __restrict__ qb, f16* __restrict__ kb, f16* __restrict__ vtb,
    float* __restrict__ out)
{
  __shared__ f16 As[128*32];   // 8KB, chunk-swizzled: phys_chunk = logical ^ ((row>>1)&3)
  __shared__ f16 Bs[128*32];
  const int tid = threadIdx.x;
  const int wid = tid >> 6, lane = tid & 63;
  const int g = lane >> 4, r = lane & 15;
  const int m0 = blockIdx.x * 128, n0 = blockIdx.y * 128;
  const int wm = (wid >> 1) * 64, wn = (wid & 1) * 64;

  f32x4 acc[4][4] = {};
  const int srow = tid >> 2;   // 0..63 (row within half-tile), 4 chunks of 16B per 64B row
  const int sch  = tid & 3;

  for (int kt = 0; kt < DM/32; ++kt) {
    const int k0 = kt * 32;
    __syncthreads();
    #pragma unroll
    for (int c = 0; c < 2; ++c) {
      int row = c*64 + srow;
      int sw = (sch ^ ((row >> 1) & 3)) * 8;   // pre-swizzled source chunk
      gl_lds16(A  + (size_t)(m0 + row) * DM + k0 + sw, (char*)As + c*4096 + tid*16);
      gl_lds16(Bt + (size_t)(n0 + row) * DM + k0 + sw, (char*)Bs + c*4096 + tid*16);
    }
    __syncthreads();
    f16x8 a[4], b[4];
    #pragma unroll
    for (int mt = 0; mt < 4; ++mt) {
      int rl = wm + mt*16 + r;
      a[mt] = *(const f16x8*)(As + rl*32 + ((g ^ ((rl >> 1) & 3)) * 8));
    }
    #pragma unroll
    for (int nt = 0; nt < 4; ++nt) {
      int cl = wn + nt*16 + r;
      b[nt] = *(const f16x8*)(Bs + cl*32 + ((g ^ ((cl >> 1) & 3)) * 8));
    }
    #pragma unroll
    for (int mt = 0; mt < 4; ++mt)
      #pragma unroll
      for (int nt = 0; nt < 4; ++nt)
        acc[mt][nt] = __builtin_amdgcn_mfma_f32_16x16x32_f16(a[mt], b[nt], acc[mt][nt], 0, 0, 0);
  }

  if (EPI == 0) {
    #pragma unroll
    for (int mt = 0; mt < 4; ++mt) {
      int row0 = m0 + wm + mt*16 + g*4;        // global token row of reg i=0
      int b_ = row0 >> 11, s0 = row0 & 2047;   // batch, seq (i spans s0..s0+3, no crossing)
      #pragma unroll
      for (int nt = 0; nt < 4; ++nt) {
        int col = n0 + wn + nt*16 + r;         // 0..3071 ; uniform h/which per 16-lane group
        float bv = bias[col];
        int h = col / 192;
        int cc = col - h*192;
        int which = cc >> 6, d = cc & 63;
        size_t bh = (size_t)(b_*NH + h);
        if (which == 2) {                       // V -> transposed [bh][d][s]
          f16x4 v;
          #pragma unroll
          for (int i = 0; i < 4; ++i) v[i] = (f16)(acc[mt][nt][i] + bv);
          *(f16x4*)(vtb + (bh*HD + d)*S_LEN + s0) = v;
        } else if (which == 0) {                // Q, pre-scaled by 1/sqrt(hd)
          #pragma unroll
          for (int i = 0; i < 4; ++i)
            qb[(bh*S_LEN + s0 + i)*HD + d] = (f16)((acc[mt][nt][i] + bv) * 0.125f);
        } else {                                // K
          #pragma unroll
          for (int i = 0; i < 4; ++i)
            kb[(bh*S_LEN + s0 + i)*HD + d] = (f16)(acc[mt][nt][i] + bv);
        }
      }
    }
  } else {
    #pragma unroll
    for (int mt = 0; mt < 4; ++mt) {
      int row0 = m0 + wm + mt*16 + g*4;
      #pragma unroll
      for (int nt = 0; nt < 4; ++nt) {
        int col = n0 + wn + nt*16 + r;
        float bv = bias[col];
        #pragma unroll
        for (int i = 0; i < 4; ++i)
          out[(size_t)(row0 + i)*DM + col] = acc[mt][nt][i] + bv;
      }
    }
  }
}

// ---------------- flash attention: 128 q-rows/block, 4 waves, K-tiles of 128 -----------
__global__ __launch_bounds__(256) void attn_kernel(
    const f16* __restrict__ qb, const f16* __restrict__ kb,
    const f16* __restrict__ vtb, f16* __restrict__ values)
{
  __shared__ f16 Ks[128*64];    // 16KB [s_k][hd], chunk ^= (row&7)   (8 x 16B chunks/row)
  __shared__ f16 Vs[64*128];    // 16KB [d][s_k],  chunk ^= (row&15)  (16 chunks/row)
  __shared__ f16 Ps[128*128];   // 32KB [q][s_k],  chunk ^= (row&15)
  const int tid = threadIdx.x;
  const int wid = tid >> 6, lane = tid & 63;
  const int g = lane >> 4, r = lane & 15;
  const int q0 = blockIdx.x * 128;
  const int bh = blockIdx.y;
  const f16* qh = qb  + (size_t)bh * S_LEN * HD;
  const f16* kh = kb  + (size_t)bh * S_LEN * HD;
  const f16* vh = vtb + (size_t)bh * HD * S_LEN;

  // Q fragments held in registers for the whole block (already scaled by 1/8)
  f16x8 qf[2][2];
  #pragma unroll
  for (int mt = 0; mt < 2; ++mt)
    #pragma unroll
    for (int ks = 0; ks < 2; ++ks)
      qf[mt][ks] = *(const f16x8*)(qh + (size_t)(q0 + wid*32 + mt*16 + r)*HD + ks*32 + g*8);

  float m_run[2][4], l_run[2][4];
  f32x4 oacc[2][4] = {};
  #pragma unroll
  for (int mt = 0; mt < 2; ++mt)
    #pragma unroll
    for (int i = 0; i < 4; ++i) { m_run[mt][i] = -1e30f; l_run[mt][i] = 0.f; }

  for (int kt = 0; kt < S_LEN/128; ++kt) {
    __syncthreads();   // previous iteration done reading Ks/Vs
    #pragma unroll
    for (int c = 0; c < 4; ++c) {
      int row = c*32 + (tid >> 3);      // K: 32 rows/call, 8 threads x 16B per 128B row
      int ck  = tid & 7;
      gl_lds16(kh + (size_t)(kt*128 + row)*HD + ((ck ^ (row & 7)) * 8),
               (char*)Ks + c*4096 + tid*16);
      int d  = c*16 + (tid >> 4);       // V: 16 d-rows/call, 16 threads x 16B per 256B row
      int cv = tid & 15;
      gl_lds16(vh + (size_t)d*S_LEN + kt*128 + ((cv ^ (d & 15)) * 8),
               (char*)Vs + c*4096 + tid*16);
    }
    __syncthreads();

    // ---- QK^T : per wave 32 q-rows x 128 k-cols ----
    f32x4 sc[2][8] = {};
    #pragma unroll
    for (int nt = 0; nt < 8; ++nt) {
      int krow = nt*16 + r;
      #pragma unroll
      for (int ks = 0; ks < 2; ++ks) {
        f16x8 bf = *(const f16x8*)(Ks + krow*64 + (((ks*4 + g) ^ (krow & 7)) * 8));
        #pragma unroll
        for (int mt = 0; mt < 2; ++mt)
          sc[mt][nt] = __builtin_amdgcn_mfma_f32_16x16x32_f16(qf[mt][ks], bf, sc[mt][nt], 0, 0, 0);
      }
    }

    // ---- online softmax (rows = mt*16 + g*4 + i; cols across 16 lanes x 8 nt) ----
    #pragma unroll
    for (int mt = 0; mt < 2; ++mt) {
      #pragma unroll
      for (int i = 0; i < 4; ++i) {
        float mx = sc[mt][0][i];
        #pragma unroll
        for (int nt = 1; nt < 8; ++nt) mx = fmaxf(mx, sc[mt][nt][i]);
        #pragma unroll
        for (int off = 1; off < 16; off <<= 1) mx = fmaxf(mx, __shfl_xor(mx, off, 16));
        float mold = m_run[mt][i];
        float mnew = fmaxf(mold, mx);
        float alpha = __expf(mold - mnew);
        m_run[mt][i] = mnew;
        float rsum = 0.f;
        int prow = wid*32 + mt*16 + g*4 + i;
        int pswz = prow & 15;
        #pragma unroll
        for (int nt = 0; nt < 8; ++nt) {
          float p = __expf(sc[mt][nt][i] - mnew);
          rsum += p;
          int colc = nt*2 + (r >> 3);                       // 16B chunk index of col
          Ps[prow*128 + ((colc ^ pswz) * 8) + (r & 7)] = (f16)p;
        }
        #pragma unroll
        for (int off = 1; off < 16; off <<= 1) rsum += __shfl_xor(rsum, off, 16);
        l_run[mt][i] = l_run[mt][i]*alpha + rsum;
        #pragma unroll
        for (int dt = 0; dt < 4; ++dt) oacc[mt][dt][i] *= alpha;
      }
    }
    __syncthreads();   // P visible (also orders vs next staging)

    // ---- PV : O += P @ V ----
    #pragma unroll
    for (int ks2 = 0; ks2 < 4; ++ks2) {
      f16x8 pa[2];
      #pragma unroll
      for (int mt = 0; mt < 2; ++mt) {
        int prow = wid*32 + mt*16 + r;
        pa[mt] = *(const f16x8*)(Ps + prow*128 + (((ks2*4 + g) ^ (prow & 15)) * 8));
      }
      #pragma unroll
      for (int dt = 0; dt < 4; ++dt) {
        int drow = dt*16 + r;
        f16x8 vb = *(const f16x8*)(Vs + drow*128 + (((ks2*4 + g) ^ (drow & 15)) * 8));
        #pragma unroll
        for (int mt = 0; mt < 2; ++mt)
          oacc[mt][dt] = __builtin_amdgcn_mfma_f32_16x16x32_f16(pa[mt], vb, oacc[mt][dt], 0, 0, 0);
      }
    }
  }

  // ---- finalize: O/l, write values in [b][s][h*64+d] layout (fp16) ----
  const int b_ = bh >> 4, h = bh & 15;
  #pragma unroll
  for (int mt = 0; mt < 2; ++mt) {
    #pragma unroll
    for (int i = 0; i < 4; ++i) {
      float inv = 1.0f / l_run[mt][i];
      int s = q0 + wid*32 + mt*16 + g*4 + i;
      #pragma unroll
      for (int dt = 0; dt < 4; ++dt)
        values[((size_t)(b_*S_LEN + s))*DM + h*64 + dt*16 + r] = (f16)(oacc[mt][dt][i] * inv);
    }
  }
}

extern "C" void kernel_launch(void* const* d_in, const int* in_sizes, int n_in,
                              void* d_out, int out_size, void* d_ws, size_t ws_size,
                              hipStream_t stream) {
  (void)in_sizes; (void)n_in; (void)out_size; (void)ws_size;
  const float* x    = (const float*)d_in[0];
  const float* Wqkv = (const float*)d_in[1];
  const float* bqkv = (const float*)d_in[2];
  const float* Wo   = (const float*)d_in[3];
  const float* bo   = (const float*)d_in[4];
  float* out = (float*)d_out;

  char* ws = (char*)d_ws;              // 48MB total
  f16* x_h    = (f16*)(ws);                        // 8MB  [4096][1024]
  f16* Wqkv_t = (f16*)(ws + ( 8ull<<20));          // 6MB  [3072][1024]
  f16* Wo_t   = (f16*)(ws + (14ull<<20));          // 2MB  [1024][1024]
  f16* qbuf   = (f16*)(ws + (16ull<<20));          // 8MB  [32][2048][64]
  f16* kbuf   = (f16*)(ws + (24ull<<20));          // 8MB  [32][2048][64]
  f16* vtbuf  = (f16*)(ws + (32ull<<20));          // 8MB  [32][64][2048]
  f16* vals   = (f16*)(ws + (40ull<<20));          // 8MB  [4096][1024]

  cvt_f16_kernel<<<dim3(NTOK*DM/8/256), dim3(256), 0, stream>>>(x, x_h, NTOK*DM);
  cvt_tr_kernel<<<dim3(NQKV/32, DM/32), dim3(32, 8), 0, stream>>>(Wqkv, Wqkv_t, DM, NQKV);
  cvt_tr_kernel<<<dim3(DM/32, DM/32),  dim3(32, 8), 0, stream>>>(Wo, Wo_t, DM, DM);

  gemm128_kernel<0><<<dim3(NTOK/128, NQKV/128), dim3(256), 0, stream>>>(
      x_h, Wqkv_t, bqkv, qbuf, kbuf, vtbuf, nullptr);

  attn_kernel<<<dim3(S_LEN/128, 2*NH), dim3(256), 0, stream>>>(qbuf, kbuf, vtbuf, vals);

  gemm128_kernel<1><<<dim3(NTOK/128, DM/128), dim3(256), 0, stream>>>(
      vals, Wo_t, bo, nullptr, nullptr, nullptr, out);
}

// Round 3
// 131.715 us; speedup vs baseline: 1.2739x; 1.2739x over previous
//
#include <hip/hip_runtime.h>
#include <stdint.h>
#include <stddef.h>

typedef _Float16 f16;
typedef _Float16 f16x8 __attribute__((ext_vector_type(8)));
typedef _Float16 f16x4 __attribute__((ext_vector_type(4)));
typedef float    f32x4 __attribute__((ext_vector_type(4)));
typedef float    f32x16 __attribute__((ext_vector_type(16)));
typedef int      i32x4 __attribute__((ext_vector_type(4)));
typedef int      i32x2 __attribute__((ext_vector_type(2)));

#define S_LEN 2048
#define DM    1024
#define NH    16
#define HD    64
#define NTOK  4096      // B*S
#define NQKV  3072      // 3*DM
#define QSCALE 0.18033688011112042f   // 0.125 * log2(e) -> scores in log2 domain
#define DEFER_THR 8.0f                // T13: P bounded by 2^8, fine in f16

#if __has_builtin(__builtin_amdgcn_exp2f)
#define EXP2(x) __builtin_amdgcn_exp2f(x)
#else
#define EXP2(x) __expf((x) * 0.69314718055994531f)
#endif

// async global->LDS, 16B per lane (wave-uniform base + lane*16 dest).
__device__ __forceinline__ void gl_lds16(const void* g, void* l) {
  __builtin_amdgcn_global_load_lds(
      (const __attribute__((address_space(1))) void*)g,
      (__attribute__((address_space(3))) void*)l, 16, 0, 0);
}

__device__ __forceinline__ void pl32_swap(int& a, int& b) {
#if __has_builtin(__builtin_amdgcn_permlane32_swap)
  i32x2 r = __builtin_amdgcn_permlane32_swap(a, b, false, false);
  a = r.x; b = r.y;
#else
  asm volatile("v_permlane32_swap_b32 %0, %1" : "+v"(a), "+v"(b));
#endif
}

// value from lane^32 (both halves end with full-row result)
__device__ __forceinline__ float swap_half(float x, int hi) {
  int a = __builtin_bit_cast(int, x);
  int b = a;
  pl32_swap(a, b);
  return __builtin_bit_cast(float, hi ? a : b);
}

__device__ __forceinline__ int pkrtz(float a, float b) {
  auto h = __builtin_amdgcn_cvt_pkrtz(a, b);   // __fp16 ext_vector(2)
  return __builtin_bit_cast(int, h);
}

__device__ __forceinline__ f16x8 mk_frag(int a, int b, int c, int d) {
  i32x4 v = {a, b, c, d};
  return __builtin_bit_cast(f16x8, v);
}

// ---------------- elementwise f32 -> f16 ----------------
__global__ __launch_bounds__(256) void cvt_f16_kernel(const float* __restrict__ in,
                                                      f16* __restrict__ out, int n) {
  int i = (blockIdx.x * 256 + threadIdx.x) * 8;
  if (i >= n) return;
  float4 a = *(const float4*)(in + i);
  float4 b = *(const float4*)(in + i + 4);
  f16x8 v = {(f16)a.x,(f16)a.y,(f16)a.z,(f16)a.w,(f16)b.x,(f16)b.y,(f16)b.z,(f16)b.w};
  *(f16x8*)(out + i) = v;
}

// ---------------- transpose+convert: in[R][C] f32 -> out[C][R] f16 ----------------
__global__ __launch_bounds__(256) void cvt_tr_kernel(const float* __restrict__ in,
                                                     f16* __restrict__ out, int R, int C) {
  __shared__ float t[32][33];
  int c0 = blockIdx.x * 32, r0 = blockIdx.y * 32;
  int tx = threadIdx.x, ty = threadIdx.y;
  #pragma unroll
  for (int i = 0; i < 4; ++i)
    t[ty + i*8][tx] = in[(size_t)(r0 + ty + i*8) * C + c0 + tx];
  __syncthreads();
  #pragma unroll
  for (int i = 0; i < 4; ++i)
    out[(size_t)(c0 + ty + i*8) * R + r0 + tx] = (f16)t[tx][ty + i*8];
}

// ---------------- 128x128x(BK=32) fp16 MFMA GEMM, A[M][1024] @ Bt[N][1024]^T ----------
template<int EPI>
__global__ __launch_bounds__(256) void gemm128_kernel(
    const f16* __restrict__ A, const f16* __restrict__ Bt,
    const float* __restrict__ bias,
    f16* __restrict__ qb, f16* __restrict__ kb, f16* __restrict__ vtb,
    float* __restrict__ out)
{
  __shared__ f16 As[128*32];
  __shared__ f16 Bs[128*32];
  const int tid = threadIdx.x;
  const int wid = tid >> 6, lane = tid & 63;
  const int g = lane >> 4, r = lane & 15;
  const int m0 = blockIdx.x * 128, n0 = blockIdx.y * 128;
  const int wm = (wid >> 1) * 64, wn = (wid & 1) * 64;

  f32x4 acc[4][4] = {};
  const int srow = tid >> 2;
  const int sch  = tid & 3;

  for (int kt = 0; kt < DM/32; ++kt) {
    const int k0 = kt * 32;
    __syncthreads();
    #pragma unroll
    for (int c = 0; c < 2; ++c) {
      int row = c*64 + srow;
      int sw = (sch ^ ((row >> 1) & 3)) * 8;
      gl_lds16(A  + (size_t)(m0 + row) * DM + k0 + sw, (char*)As + c*4096 + tid*16);
      gl_lds16(Bt + (size_t)(n0 + row) * DM + k0 + sw, (char*)Bs + c*4096 + tid*16);
    }
    __syncthreads();
    f16x8 a[4], b[4];
    #pragma unroll
    for (int mt = 0; mt < 4; ++mt) {
      int rl = wm + mt*16 + r;
      a[mt] = *(const f16x8*)(As + rl*32 + ((g ^ ((rl >> 1) & 3)) * 8));
    }
    #pragma unroll
    for (int nt = 0; nt < 4; ++nt) {
      int cl = wn + nt*16 + r;
      b[nt] = *(const f16x8*)(Bs + cl*32 + ((g ^ ((cl >> 1) & 3)) * 8));
    }
    #pragma unroll
    for (int mt = 0; mt < 4; ++mt)
      #pragma unroll
      for (int nt = 0; nt < 4; ++nt)
        acc[mt][nt] = __builtin_amdgcn_mfma_f32_16x16x32_f16(a[mt], b[nt], acc[mt][nt], 0, 0, 0);
  }

  if (EPI == 0) {
    #pragma unroll
    for (int mt = 0; mt < 4; ++mt) {
      int row0 = m0 + wm + mt*16 + g*4;
      int b_ = row0 >> 11, s0 = row0 & 2047;
      #pragma unroll
      for (int nt = 0; nt < 4; ++nt) {
        int col = n0 + wn + nt*16 + r;
        float bv = bias[col];
        int h = col / 192;
        int cc = col - h*192;
        int which = cc >> 6, d = cc & 63;
        size_t bh = (size_t)(b_*NH + h);
        if (which == 2) {                       // V -> transposed [bh][d][s]
          f16x4 v;
          #pragma unroll
          for (int i = 0; i < 4; ++i) v[i] = (f16)(acc[mt][nt][i] + bv);
          *(f16x4*)(vtb + (bh*HD + d)*S_LEN + s0) = v;
        } else if (which == 0) {                // Q, pre-scaled to log2 domain
          #pragma unroll
          for (int i = 0; i < 4; ++i)
            qb[(bh*S_LEN + s0 + i)*HD + d] = (f16)((acc[mt][nt][i] + bv) * QSCALE);
        } else {                                // K
          #pragma unroll
          for (int i = 0; i < 4; ++i)
            kb[(bh*S_LEN + s0 + i)*HD + d] = (f16)(acc[mt][nt][i] + bv);
        }
      }
    }
  } else {
    #pragma unroll
    for (int mt = 0; mt < 4; ++mt) {
      int row0 = m0 + wm + mt*16 + g*4;
      #pragma unroll
      for (int nt = 0; nt < 4; ++nt) {
        int col = n0 + wn + nt*16 + r;
        float bv = bias[col];
        #pragma unroll
        for (int i = 0; i < 4; ++i)
          out[(size_t)(row0 + i)*DM + col] = acc[mt][nt][i] + bv;
      }
    }
  }
}

// ---------------- flash attention v2: swapped-QK 32x32, in-register softmax ----------
// 4 waves x 32 q-rows = 128 q/block; KVBLK=64, double-buffered K/V in LDS (8KB each).
// K tile: [64 k][64 d] f16, 16B-chunk swizzle: phys = chunk ^ (row&7).
// V tile: [64 d][64 k] f16 (V^T), same swizzle.
__device__ __forceinline__ void attn_stage(const f16* __restrict__ kh,
                                           const f16* __restrict__ vh,
                                           int kt, f16* ksb, f16* vsb, int tid) {
  int row = tid >> 3, ch = tid & 7;
  int sw = (ch ^ (row & 7)) << 3;            // pre-swizzled source chunk (elements)
  const f16* ksrc = kh + (size_t)(kt*64 + row) * HD + sw;
  gl_lds16(ksrc,          (char*)ksb + tid*16);
  gl_lds16(ksrc + 32*HD,  (char*)ksb + 4096 + tid*16);
  const f16* vsrc = vh + (size_t)row * S_LEN + kt*64 + sw;
  gl_lds16(vsrc,              (char*)vsb + tid*16);
  gl_lds16(vsrc + 32*S_LEN,   (char*)vsb + 4096 + tid*16);
}

__global__ __launch_bounds__(256) void attn_kernel(
    const f16* __restrict__ qb, const f16* __restrict__ kb,
    const f16* __restrict__ vtb, f16* __restrict__ values)
{
  __shared__ f16 Ks[2][64*64];     // 2 x 8KB
  __shared__ f16 Vs[2][64*64];     // 2 x 8KB
  __shared__ float xbuf[4][32];    // per-wave alpha / 1/l broadcast
  const int tid = threadIdx.x;
  const int wid = tid >> 6, lane = tid & 63;
  const int ql = lane & 31, hi = lane >> 5;
  const int q0 = blockIdx.x * 128 + wid * 32;
  const int bh = blockIdx.y;
  const f16* qh = qb  + (size_t)bh * S_LEN * HD;
  const f16* kh = kb  + (size_t)bh * S_LEN * HD;
  const f16* vh = vtb + (size_t)bh * HD * S_LEN;

  // Q B-fragments (held all block): lane(q=ql,hi) holds Q[q0+ql][dk*16+hi*8 .. +7]
  f16x8 qf[4];
  #pragma unroll
  for (int dk = 0; dk < 4; ++dk)
    qf[dk] = *(const f16x8*)(qh + (size_t)(q0 + ql)*HD + dk*16 + hi*8);

  float m_run = -1e30f, l_run = 0.f;
  f32x16 o0 = {}, o1 = {};

  attn_stage(kh, vh, 0, Ks[0], Vs[0], tid);
  __syncthreads();

  for (int kt = 0; kt < S_LEN/64; ++kt) {
    const int cur = kt & 1;
    if (kt + 1 < S_LEN/64)
      attn_stage(kh, vh, kt + 1, Ks[cur ^ 1], Vs[cur ^ 1], tid);

    const f16* KsC = Ks[cur];
    const f16* VsC = Vs[cur];
    const int swz = (ql & 7);

    // ---- QK^T swapped: S^T tiles, C[k][q]: q = ql, k = (reg&3)+8*(reg>>2)+4*hi (+32*kt2)
    f32x16 s0 = {}, s1 = {};
    __builtin_amdgcn_s_setprio(1);
    #pragma unroll
    for (int dk = 0; dk < 4; ++dk) {
      int pch = ((dk*2 + hi) ^ swz) * 8;
      f16x8 kf0 = *(const f16x8*)(KsC + (ql)*64      + pch);
      f16x8 kf1 = *(const f16x8*)(KsC + (32 + ql)*64 + pch);
      s0 = __builtin_amdgcn_mfma_f32_32x32x16_f16(kf0, qf[dk], s0, 0, 0, 0);
      s1 = __builtin_amdgcn_mfma_f32_32x32x16_f16(kf1, qf[dk], s1, 0, 0, 0);
    }
    __builtin_amdgcn_s_setprio(0);

    // ---- in-register row max (32 vals + cross-half swap) ----
    float tm[8];
    #pragma unroll
    for (int i = 0; i < 8; ++i)
      tm[i] = fmaxf(fmaxf(s0[i], s0[i+8]), fmaxf(s1[i], s1[i+8]));
    #pragma unroll
    for (int i = 0; i < 4; ++i) tm[i] = fmaxf(tm[i], tm[i+4]);
    tm[0] = fmaxf(fmaxf(tm[0], tm[1]), fmaxf(tm[2], tm[3]));
    float rmax = fmaxf(tm[0], swap_half(tm[0], hi));

    // ---- T13 defer-max: only rescale when max grew past threshold ----
    if (!__all(rmax - m_run <= DEFER_THR)) {
      float mnew = fmaxf(m_run, rmax);
      float alpha = EXP2(m_run - mnew);
      m_run = mnew;
      l_run *= alpha;
      xbuf[wid][ql] = alpha;               // both halves write same value
      f32x4 av[4];
      #pragma unroll
      for (int t = 0; t < 4; ++t)
        av[t] = *(const f32x4*)&xbuf[wid][hi*4 + t*8];
      #pragma unroll
      for (int t = 0; t < 4; ++t)
        #pragma unroll
        for (int i = 0; i < 4; ++i) {
          o0[t*4+i] *= av[t][i];
          o1[t*4+i] *= av[t][i];
        }
    }

    // ---- P = exp2(S - m), row sum ----
    float es[16];
    #pragma unroll
    for (int i = 0; i < 16; ++i) {
      s0[i] = EXP2(s0[i] - m_run);
      s1[i] = EXP2(s1[i] - m_run);
      es[i] = s0[i] + s1[i];
    }
    #pragma unroll
    for (int i = 0; i < 8; ++i) es[i] += es[i+8];
    #pragma unroll
    for (int i = 0; i < 4; ++i) es[i] += es[i+4];
    float rsum = (es[0] + es[1]) + (es[2] + es[3]);
    rsum += swap_half(rsum, hi);
    l_run += rsum;

    // ---- pack P -> A-fragments (cvt_pkrtz + permlane32_swap), all in registers ----
    f16x8 pf[4];
    {
      int a = pkrtz(s0[0], s0[1]), b = pkrtz(s0[2], s0[3]);
      int c = pkrtz(s0[4], s0[5]), d = pkrtz(s0[6], s0[7]);
      pl32_swap(a, c); pl32_swap(b, d);
      pf[0] = mk_frag(a, b, c, d);
      a = pkrtz(s0[8],  s0[9]);  b = pkrtz(s0[10], s0[11]);
      c = pkrtz(s0[12], s0[13]); d = pkrtz(s0[14], s0[15]);
      pl32_swap(a, c); pl32_swap(b, d);
      pf[1] = mk_frag(a, b, c, d);
      a = pkrtz(s1[0], s1[1]); b = pkrtz(s1[2], s1[3]);
      c = pkrtz(s1[4], s1[5]); d = pkrtz(s1[6], s1[7]);
      pl32_swap(a, c); pl32_swap(b, d);
      pf[2] = mk_frag(a, b, c, d);
      a = pkrtz(s1[8],  s1[9]);  b = pkrtz(s1[10], s1[11]);
      c = pkrtz(s1[12], s1[13]); d = pkrtz(s1[14], s1[15]);
      pl32_swap(a, c); pl32_swap(b, d);
      pf[3] = mk_frag(a, b, c, d);
    }

    // ---- PV: O[q][d] += P @ V, B-frags straight from V^T tile ----
    __builtin_amdgcn_s_setprio(1);
    #pragma unroll
    for (int w = 0; w < 4; ++w) {
      int pch = ((w*2 + hi) ^ swz) * 8;
      f16x8 vf0 = *(const f16x8*)(VsC + (ql)*64      + pch);
      f16x8 vf1 = *(const f16x8*)(VsC + (32 + ql)*64 + pch);
      o0 = __builtin_amdgcn_mfma_f32_32x32x16_f16(pf[w], vf0, o0, 0, 0, 0);
      o1 = __builtin_amdgcn_mfma_f32_32x32x16_f16(pf[w], vf1, o1, 0, 0, 0);
    }
    __builtin_amdgcn_s_setprio(0);

    __syncthreads();   // staged next tile ready; all waves done with cur
  }

  // ---- finalize: O/l, write vals [b][s][h*64+d] ----
  float linv = 1.0f / l_run;
  xbuf[wid][ql] = linv;
  f32x4 lv[4];
  #pragma unroll
  for (int t = 0; t < 4; ++t)
    lv[t] = *(const f32x4*)&xbuf[wid][hi*4 + t*8];

  const int b_ = bh >> 4, h = bh & 15;
  #pragma unroll
  for (int t = 0; t < 4; ++t)
    #pragma unroll
    for (int i = 0; i < 4; ++i) {
      int qrow = q0 + 4*hi + 8*t + i;
      size_t base = (size_t)(b_*S_LEN + qrow) * DM + h*HD + ql;
      values[base]      = (f16)(o0[t*4+i] * lv[t][i]);
      values[base + 32] = (f16)(o1[t*4+i] * lv[t][i]);
    }
}

extern "C" void kernel_launch(void* const* d_in, const int* in_sizes, int n_in,
                              void* d_out, int out_size, void* d_ws, size_t ws_size,
                              hipStream_t stream) {
  (void)in_sizes; (void)n_in; (void)out_size; (void)ws_size;
  const float* x    = (const float*)d_in[0];
  const float* Wqkv = (const float*)d_in[1];
  const float* bqkv = (const float*)d_in[2];
  const float* Wo   = (const float*)d_in[3];
  const float* bo   = (const float*)d_in[4];
  float* out = (float*)d_out;

  char* ws = (char*)d_ws;
  f16* x_h    = (f16*)(ws);                        // 8MB  [4096][1024]
  f16* Wqkv_t = (f16*)(ws + ( 8ull<<20));          // 6MB  [3072][1024]
  f16* Wo_t   = (f16*)(ws + (14ull<<20));          // 2MB  [1024][1024]
  f16* qbuf   = (f16*)(ws + (16ull<<20));          // 8MB  [32][2048][64]
  f16* kbuf   = (f16*)(ws + (24ull<<20));          // 8MB  [32][2048][64]
  f16* vtbuf  = (f16*)(ws + (32ull<<20));          // 8MB  [32][64][2048]
  f16* vals   = (f16*)(ws + (40ull<<20));          // 8MB  [4096][1024]

  cvt_f16_kernel<<<dim3(NTOK*DM/8/256), dim3(256), 0, stream>>>(x, x_h, NTOK*DM);
  cvt_tr_kernel<<<dim3(NQKV/32, DM/32), dim3(32, 8), 0, stream>>>(Wqkv, Wqkv_t, DM, NQKV);
  cvt_tr_kernel<<<dim3(DM/32, DM/32),  dim3(32, 8), 0, stream>>>(Wo, Wo_t, DM, DM);

  gemm128_kernel<0><<<dim3(NTOK/128, NQKV/128), dim3(256), 0, stream>>>(
      x_h, Wqkv_t, bqkv, qbuf, kbuf, vtbuf, nullptr);

  attn_kernel<<<dim3(S_LEN/128, 2*NH), dim3(256), 0, stream>>>(qbuf, kbuf, vtbuf, vals);

  gemm128_kernel<1><<<dim3(NTOK/128, DM/128), dim3(256), 0, stream>>>(
      vals, Wo_t, bo, nullptr, nullptr, nullptr, out);
}